// Round 1
// baseline (1104.806 us; speedup 1.0000x reference)
//
#include <hip/hip_runtime.h>
#include <math.h>

#define F 128
#define TWO_F 256
#define BN_EPS 1e-5f

__device__ __forceinline__ float gelu_exact(float x) {
    return 0.5f * x * (1.0f + erff(x * 0.70710678118654752f));
}

// Fold BN scale into weights: Wf[k][j] = s[k] * W[k][j], s = gamma/sqrt(var+eps)
__global__ void fold_weights(const float* __restrict__ pre_w,
                             const float* __restrict__ pre_g, const float* __restrict__ pre_v,
                             const float* __restrict__ upd_w,
                             const float* __restrict__ upd_g, const float* __restrict__ upd_v,
                             float* __restrict__ W1f, float* __restrict__ W2f) {
    int idx = blockIdx.x * blockDim.x + threadIdx.x;
    if (idx < F * F) {
        int k = idx >> 7;
        float s = pre_g[k] * rsqrtf(pre_v[k] + BN_EPS);
        W1f[idx] = s * pre_w[idx];
    }
    if (idx < TWO_F * F) {
        int k = idx >> 7;
        float s = upd_g[k] * rsqrtf(upd_v[k] + BN_EPS);
        W2f[idx] = s * upd_w[idx];
    }
}

// Fold BN shift into bias: bf[j] = b[j] + sum_k t[k]*W[k][j], t = beta - mean*s
__global__ void fold_bias(const float* __restrict__ pre_w, const float* __restrict__ pre_b,
                          const float* __restrict__ pre_g, const float* __restrict__ pre_be,
                          const float* __restrict__ pre_m, const float* __restrict__ pre_v,
                          const float* __restrict__ upd_w, const float* __restrict__ upd_b,
                          const float* __restrict__ upd_g, const float* __restrict__ upd_be,
                          const float* __restrict__ upd_m, const float* __restrict__ upd_v,
                          float* __restrict__ b1f, float* __restrict__ b2f) {
    int tid = threadIdx.x;
    if (tid < F) {
        int j = tid;
        float acc = pre_b[j];
        for (int k = 0; k < F; ++k) {
            float s = pre_g[k] * rsqrtf(pre_v[k] + BN_EPS);
            float t = pre_be[k] - pre_m[k] * s;
            acc = fmaf(t, pre_w[k * F + j], acc);
        }
        b1f[j] = acc;
    } else {
        int j = tid - F;
        float acc = upd_b[j];
        for (int k = 0; k < TWO_F; ++k) {
            float s = upd_g[k] * rsqrtf(upd_v[k] + BN_EPS);
            float t = upd_be[k] - upd_m[k] * s;
            acc = fmaf(t, upd_w[k * F + j], acc);
        }
        b2f[j] = acc;
    }
}

// Edge pass: for each edge e: y = gelu(nodes[nbr] @ W1f + b1f) * ew[e];
// atomicAdd into agg[dst], deg[dst] += 1.
// Block = 256 threads = 2 edge slots x 128 output features.
__global__ __launch_bounds__(256) void edge_pass(
    const float* __restrict__ nodes, const int* __restrict__ edges,
    const float* __restrict__ ew,
    const float* __restrict__ W1f, const float* __restrict__ b1f,
    float* __restrict__ agg, float* __restrict__ deg, int nEdges) {
    __shared__ float xs[2][F];
    const int j = threadIdx.x & (F - 1);
    const int slot = threadIdx.x >> 7;

    // weight column j in registers (fully unrolled indexing)
    float w[F];
    #pragma unroll
    for (int k = 0; k < F; ++k) w[k] = W1f[k * F + j];
    const float bj = b1f[j];

    for (int p = blockIdx.x; p * 2 < nEdges; p += gridDim.x) {
        const int e = p * 2 + slot;
        const bool active = e < nEdges;
        int nbr = 0, dst = 0;
        float wgt = 0.f;
        if (active) {
            nbr = edges[nEdges + e];   // edges[1] = neighbour idx
            dst = edges[e];            // edges[0] = destination
            wgt = ew[e];
        }
        __syncthreads();
        if (active) xs[slot][j] = nodes[(size_t)nbr * F + j];
        __syncthreads();
        if (active) {
            float acc = bj;
            const float4* xv = reinterpret_cast<const float4*>(xs[slot]);
            #pragma unroll
            for (int k4 = 0; k4 < F / 4; ++k4) {
                float4 x4 = xv[k4];
                acc = fmaf(x4.x, w[4 * k4 + 0], acc);
                acc = fmaf(x4.y, w[4 * k4 + 1], acc);
                acc = fmaf(x4.z, w[4 * k4 + 2], acc);
                acc = fmaf(x4.w, w[4 * k4 + 3], acc);
            }
            float val = gelu_exact(acc) * wgt;
            atomicAdd(&agg[(size_t)dst * F + j], val);
            if (j == 0) atomicAdd(&deg[dst], 1.0f);
        }
    }
}

// Node pass: emb = [nodes[n], agg[n]/(deg*F)]; out[n] = gelu(emb @ W2f + b2f).
// Block = 256 threads = 128 features x 2 k-halves.
__global__ __launch_bounds__(256) void node_pass(
    const float* __restrict__ nodes, const float* __restrict__ agg,
    const float* __restrict__ deg,
    const float* __restrict__ W2f, const float* __restrict__ b2f,
    float* __restrict__ out, int nNodes) {
    __shared__ float es[TWO_F];
    __shared__ float partial[F];
    const int j = threadIdx.x & (F - 1);
    const int h = threadIdx.x >> 7;   // which half of k

    float w[F];
    #pragma unroll
    for (int k = 0; k < F; ++k) w[k] = W2f[(h * F + k) * F + j];
    const float bj = b2f[j];

    for (int n = blockIdx.x; n < nNodes; n += gridDim.x) {
        __syncthreads();
        if (h == 0) {
            es[j] = nodes[(size_t)n * F + j];
        } else {
            float d = deg[n];
            float inv = (d > 0.f) ? 1.0f / (d * (float)F) : 0.f;  // counter = deg*F quirk
            es[F + j] = agg[(size_t)n * F + j] * inv;
        }
        __syncthreads();
        float acc = 0.f;
        const float4* evv = reinterpret_cast<const float4*>(&es[h * F]);
        #pragma unroll
        for (int k4 = 0; k4 < F / 4; ++k4) {
            float4 x4 = evv[k4];
            acc = fmaf(x4.x, w[4 * k4 + 0], acc);
            acc = fmaf(x4.y, w[4 * k4 + 1], acc);
            acc = fmaf(x4.z, w[4 * k4 + 2], acc);
            acc = fmaf(x4.w, w[4 * k4 + 3], acc);
        }
        if (h == 1) partial[j] = acc;
        __syncthreads();
        if (h == 0) {
            float tot = acc + partial[j] + bj;
            out[(size_t)n * F + j] = gelu_exact(tot);
        }
    }
}

extern "C" void kernel_launch(void* const* d_in, const int* in_sizes, int n_in,
                              void* d_out, int out_size, void* d_ws, size_t ws_size,
                              hipStream_t stream) {
    const float* nodes  = (const float*)d_in[0];
    const int*   edges  = (const int*)d_in[1];
    const float* ew     = (const float*)d_in[2];
    const float* pre_g  = (const float*)d_in[3];
    const float* pre_be = (const float*)d_in[4];
    const float* pre_m  = (const float*)d_in[5];
    const float* pre_v  = (const float*)d_in[6];
    const float* pre_w  = (const float*)d_in[7];
    const float* pre_b  = (const float*)d_in[8];
    const float* upd_g  = (const float*)d_in[9];
    const float* upd_be = (const float*)d_in[10];
    const float* upd_m  = (const float*)d_in[11];
    const float* upd_v  = (const float*)d_in[12];
    const float* upd_w  = (const float*)d_in[13];
    const float* upd_b  = (const float*)d_in[14];
    float* out = (float*)d_out;

    const int nNodes = in_sizes[0] / F;
    const int nEdges = in_sizes[2];

    // workspace layout: agg [nNodes*F] | deg [nNodes] | W1f [F*F] | b1f [F] | W2f [2F*F] | b2f [F]
    float* agg = (float*)d_ws;
    float* deg = agg + (size_t)nNodes * F;
    float* W1f = deg + nNodes;
    float* b1f = W1f + F * F;
    float* W2f = b1f + F;
    float* b2f = W2f + TWO_F * F;

    // zero the accumulators (ws is poisoned 0xAA before every call)
    hipMemsetAsync(d_ws, 0, ((size_t)nNodes * F + nNodes) * sizeof(float), stream);

    fold_weights<<<(TWO_F * F + 255) / 256, 256, 0, stream>>>(
        pre_w, pre_g, pre_v, upd_w, upd_g, upd_v, W1f, W2f);
    fold_bias<<<1, 256, 0, stream>>>(
        pre_w, pre_b, pre_g, pre_be, pre_m, pre_v,
        upd_w, upd_b, upd_g, upd_be, upd_m, upd_v, b1f, b2f);

    edge_pass<<<2048, 256, 0, stream>>>(nodes, edges, ew, W1f, b1f, agg, deg, nEdges);
    node_pass<<<2048, 256, 0, stream>>>(nodes, agg, deg, W2f, b2f, out, nNodes);
}

// Round 2
// 549.381 us; speedup vs baseline: 2.0110x; 2.0110x over previous
//
#include <hip/hip_runtime.h>
#include <math.h>

#define F 128
#define TWO_F 256
#define BN_EPS 1e-5f

typedef unsigned short ushort_t;
typedef __attribute__((ext_vector_type(8))) short bfrag;   // 8 bf16 (4 VGPRs)
typedef __attribute__((ext_vector_type(4))) float ffrag;   // 4 fp32 acc

__device__ __forceinline__ float gelu_exact(float x) {
    return 0.5f * x * (1.0f + erff(x * 0.70710678118654752f));
}

// fp32 -> bf16 round-to-nearest-even
__device__ __forceinline__ ushort_t f2bf(float x) {
    unsigned int u = __float_as_uint(x);
    u = (u + 0x7FFFu + ((u >> 16) & 1u)) >> 16;
    return (ushort_t)u;
}
__device__ __forceinline__ unsigned int pk2(float a, float b) {
    return (unsigned int)f2bf(a) | ((unsigned int)f2bf(b) << 16);
}

// ---------------- fold kernels ----------------
// W1T[n][k] = bf16(s1[k] * pre_w[k][n])   (128x128, k contiguous)
// W2T[n][k] = bf16(s2[k] * upd_w[k][n])   (128x256, k contiguous)
__global__ void fold_wT(const float* __restrict__ pre_w,
                        const float* __restrict__ g1, const float* __restrict__ v1,
                        const float* __restrict__ upd_w,
                        const float* __restrict__ g2, const float* __restrict__ v2,
                        ushort_t* __restrict__ W1T, ushort_t* __restrict__ W2T) {
    int idx = blockIdx.x * blockDim.x + threadIdx.x;
    if (idx < F * F) {
        int k = idx & (F - 1), n = idx >> 7;
        float s = g1[k] * rsqrtf(v1[k] + BN_EPS);
        W1T[idx] = f2bf(s * pre_w[k * F + n]);
    }
    if (idx < TWO_F * F) {
        int k = idx & (TWO_F - 1), n = idx >> 8;
        float s = g2[k] * rsqrtf(v2[k] + BN_EPS);
        W2T[idx] = f2bf(s * upd_w[k * F + n]);
    }
}

// bf[j] = b[j] + sum_k (beta[k]-mean[k]*s[k]) * W[k][j]  (fp32, exact)
__global__ void fold_bias(const float* __restrict__ pre_w, const float* __restrict__ pre_b,
                          const float* __restrict__ pre_g, const float* __restrict__ pre_be,
                          const float* __restrict__ pre_m, const float* __restrict__ pre_v,
                          const float* __restrict__ upd_w, const float* __restrict__ upd_b,
                          const float* __restrict__ upd_g, const float* __restrict__ upd_be,
                          const float* __restrict__ upd_m, const float* __restrict__ upd_v,
                          float* __restrict__ b1f, float* __restrict__ b2f) {
    int tid = threadIdx.x;
    if (tid < F) {
        int j = tid;
        float acc = pre_b[j];
        for (int k = 0; k < F; ++k) {
            float s = pre_g[k] * rsqrtf(pre_v[k] + BN_EPS);
            float t = pre_be[k] - pre_m[k] * s;
            acc = fmaf(t, pre_w[k * F + j], acc);
        }
        b1f[j] = acc;
    } else {
        int j = tid - F;
        float acc = upd_b[j];
        for (int k = 0; k < TWO_F; ++k) {
            float s = upd_g[k] * rsqrtf(upd_v[k] + BN_EPS);
            float t = upd_be[k] - upd_m[k] * s;
            acc = fmaf(t, upd_w[k * F + j], acc);
        }
        b2f[j] = acc;
    }
}

// nodes fp32 -> bf16 (row-major, 8 elems/thread)
__global__ void convert_x(const float* __restrict__ nodes, ushort_t* __restrict__ Xb, int n8) {
    int i = blockIdx.x * blockDim.x + threadIdx.x;
    if (i >= n8) return;
    const float4* s = reinterpret_cast<const float4*>(nodes) + 2 * (size_t)i;
    float4 a = s[0], b = s[1];
    uint4 p;
    p.x = pk2(a.x, a.y); p.y = pk2(a.z, a.w);
    p.z = pk2(b.x, b.y); p.w = pk2(b.z, b.w);
    reinterpret_cast<uint4*>(Xb)[i] = p;
}

// degree histogram
__global__ void hist(const int* __restrict__ edges, int* __restrict__ counts, int nEdges) {
    for (int i = blockIdx.x * blockDim.x + threadIdx.x; i < nEdges; i += gridDim.x * blockDim.x)
        atomicAdd(&counts[edges[i]], 1);
}

// ---------------- edge GEMM (MFMA) + atomic scatter ----------------
// 64 edges/block. Y[e][:] = gelu(Xb[nbr[e]] @ W1T^T + b1) * ew[e]; atomicAdd into agg[dst].
__global__ __launch_bounds__(256) void edge_mfma(
    const ushort_t* __restrict__ Xb, const int* __restrict__ edges,
    const float* __restrict__ ew, const ushort_t* __restrict__ W1T,
    const float* __restrict__ b1f, float* __restrict__ agg, int nEdges) {
    __shared__ ushort_t As[64 * F];      // 16 KB
    __shared__ ushort_t Ws[F * F];       // 32 KB
    __shared__ float ews[64];
    __shared__ int dsts[64];
    __shared__ float bs[F];

    const int t = threadIdx.x;
    const int base = blockIdx.x * 64;

    // stage A tile: 4 threads per edge row, 32 bf16 (64B) each
    {
        int row = t >> 2, q = t & 3;
        int e = base + row;
        int nbr = (e < nEdges) ? edges[nEdges + e] : 0;
        const uint4* src = reinterpret_cast<const uint4*>(Xb + (size_t)nbr * F + q * 32);
        uint4* dst = reinterpret_cast<uint4*>(As + row * F + q * 32);
        #pragma unroll
        for (int i = 0; i < 4; ++i) dst[i] = src[i];
    }
    // stage W1T (32 KB): 2048 uint4 / 256 threads
    {
        const uint4* src = reinterpret_cast<const uint4*>(W1T);
        uint4* dst = reinterpret_cast<uint4*>(Ws);
        #pragma unroll
        for (int i = 0; i < 8; ++i) dst[t + i * 256] = src[t + i * 256];
    }
    if (t < 64) {
        int e = base + t;
        ews[t] = (e < nEdges) ? ew[e] : 0.f;
        dsts[t] = (e < nEdges) ? edges[e] : 0;
    }
    if (t < F) bs[t] = b1f[t];
    __syncthreads();

    const int lane = t & 63, w = t >> 6;     // 4 waves x 16 edge rows
    const int m = lane & 15, quad = lane >> 4;

    ffrag acc[8];
    #pragma unroll
    for (int c = 0; c < 8; ++c) acc[c] = (ffrag){0.f, 0.f, 0.f, 0.f};

    #pragma unroll
    for (int kk = 0; kk < 4; ++kk) {
        int k0 = kk * 32 + quad * 8;
        bfrag a = *reinterpret_cast<const bfrag*>(As + (w * 16 + m) * F + k0);
        #pragma unroll
        for (int c = 0; c < 8; ++c) {
            bfrag b = *reinterpret_cast<const bfrag*>(Ws + (c * 16 + m) * F + k0);
            acc[c] = __builtin_amdgcn_mfma_f32_16x16x32_bf16(a, b, acc[c], 0, 0, 0);
        }
    }

    // epilogue: C layout col=lane&15, row=quad*4+i
    #pragma unroll
    for (int c = 0; c < 8; ++c) {
        int feat = c * 16 + m;
        float bj = bs[feat];
        #pragma unroll
        for (int i = 0; i < 4; ++i) {
            int row = w * 16 + quad * 4 + i;
            int e = base + row;
            if (e < nEdges) {
                float v = gelu_exact(acc[c][i] + bj) * ews[row];
                atomicAdd(&agg[(size_t)dsts[row] * F + feat], v);
            }
        }
    }
}

// ---------------- node GEMM (MFMA) ----------------
// 64 nodes/block. emb=[Xb[n], bf16(agg[n]/(deg*F))]; out = gelu(emb @ W2T^T + b2)  (fp32 out)
__global__ __launch_bounds__(256) void node_mfma(
    const ushort_t* __restrict__ Xb, const float* __restrict__ agg,
    const int* __restrict__ counts, const ushort_t* __restrict__ W2T,
    const float* __restrict__ b2f, float* __restrict__ out, int nNodes) {
    __shared__ ushort_t As[64 * TWO_F];  // 32 KB
    __shared__ float bs[F];

    const int t = threadIdx.x;
    const int base = blockIdx.x * 64;

    {
        int r = t >> 2, q = t & 3;
        int n = base + r;
        if (n < nNodes) {
            if (q < 2) {  // node features, already bf16
                const uint4* src = reinterpret_cast<const uint4*>(Xb + (size_t)n * F + q * 64);
                uint4* dst = reinterpret_cast<uint4*>(As + r * TWO_F + q * 64);
                #pragma unroll
                for (int i = 0; i < 8; ++i) dst[i] = src[i];
            } else {      // normalized aggregation, fp32 -> bf16
                int cnt = counts[n];
                float inv = (cnt > 0) ? 1.0f / ((float)cnt * (float)F) : 0.f;  // counter = deg*F
                const float4* src = reinterpret_cast<const float4*>(agg + (size_t)n * F + (q - 2) * 64);
                uint4* dst = reinterpret_cast<uint4*>(As + r * TWO_F + F + (q - 2) * 64);
                #pragma unroll
                for (int i = 0; i < 8; ++i) {
                    float4 x0 = src[2 * i], x1 = src[2 * i + 1];
                    uint4 p;
                    p.x = pk2(x0.x * inv, x0.y * inv); p.y = pk2(x0.z * inv, x0.w * inv);
                    p.z = pk2(x1.x * inv, x1.y * inv); p.w = pk2(x1.z * inv, x1.w * inv);
                    dst[i] = p;
                }
            }
        } else {  // zero-fill padding rows
            uint4 z = {0, 0, 0, 0};
            uint4* dst = reinterpret_cast<uint4*>(As + r * TWO_F + q * 64);
            #pragma unroll
            for (int i = 0; i < 8; ++i) dst[i] = z;
        }
    }
    if (t < F) bs[t] = b2f[t];
    __syncthreads();

    const int lane = t & 63, w = t >> 6;  // 4 waves x 16 node rows
    const int m = lane & 15, quad = lane >> 4;

    ffrag acc[8];
    #pragma unroll
    for (int c = 0; c < 8; ++c) acc[c] = (ffrag){0.f, 0.f, 0.f, 0.f};

    #pragma unroll
    for (int kk = 0; kk < 8; ++kk) {
        int k0 = kk * 32 + quad * 8;
        bfrag a = *reinterpret_cast<const bfrag*>(As + (w * 16 + m) * TWO_F + k0);
        #pragma unroll
        for (int c = 0; c < 8; ++c) {
            bfrag b = *reinterpret_cast<const bfrag*>(W2T + (size_t)(c * 16 + m) * TWO_F + k0);
            acc[c] = __builtin_amdgcn_mfma_f32_16x16x32_bf16(a, b, acc[c], 0, 0, 0);
        }
    }

    #pragma unroll
    for (int c = 0; c < 8; ++c) {
        int feat = c * 16 + m;
        float bj = bs[feat];
        #pragma unroll
        for (int i = 0; i < 4; ++i) {
            int n = base + w * 16 + quad * 4 + i;
            if (n < nNodes) out[(size_t)n * F + feat] = gelu_exact(acc[c][i] + bj);
        }
    }
}

extern "C" void kernel_launch(void* const* d_in, const int* in_sizes, int n_in,
                              void* d_out, int out_size, void* d_ws, size_t ws_size,
                              hipStream_t stream) {
    const float* nodes  = (const float*)d_in[0];
    const int*   edges  = (const int*)d_in[1];
    const float* ew     = (const float*)d_in[2];
    const float* pre_g  = (const float*)d_in[3];
    const float* pre_be = (const float*)d_in[4];
    const float* pre_m  = (const float*)d_in[5];
    const float* pre_v  = (const float*)d_in[6];
    const float* pre_w  = (const float*)d_in[7];
    const float* pre_b  = (const float*)d_in[8];
    const float* upd_g  = (const float*)d_in[9];
    const float* upd_be = (const float*)d_in[10];
    const float* upd_m  = (const float*)d_in[11];
    const float* upd_v  = (const float*)d_in[12];
    const float* upd_w  = (const float*)d_in[13];
    const float* upd_b  = (const float*)d_in[14];
    float* out = (float*)d_out;

    const int nNodes = in_sizes[0] / F;
    const int nEdges = in_sizes[2];

    // ws layout (all offsets 16B-aligned):
    // agg fp32 [nNodes*F] | counts int [nNodes] | b1f f32[128] | b2f f32[128]
    // | W1T bf16 [128*128] | W2T bf16 [128*256] | Xb bf16 [nNodes*128]
    char* p = (char*)d_ws;
    float*    agg    = (float*)p;                 p += (size_t)nNodes * F * 4;
    int*      counts = (int*)p;                   p += (size_t)nNodes * 4;
    float*    b1f    = (float*)p;                 p += F * 4;
    float*    b2f    = (float*)p;                 p += F * 4;
    ushort_t* W1T    = (ushort_t*)p;              p += F * F * 2;
    ushort_t* W2T    = (ushort_t*)p;              p += TWO_F * F * 2;
    ushort_t* Xb     = (ushort_t*)p;

    // zero agg + counts (contiguous)
    hipMemsetAsync(agg, 0, ((size_t)nNodes * F + nNodes) * sizeof(float), stream);

    fold_wT<<<(TWO_F * F + 255) / 256, 256, 0, stream>>>(
        pre_w, pre_g, pre_v, upd_w, upd_g, upd_v, W1T, W2T);
    fold_bias<<<1, 256, 0, stream>>>(
        pre_w, pre_b, pre_g, pre_be, pre_m, pre_v,
        upd_w, upd_b, upd_g, upd_be, upd_m, upd_v, b1f, b2f);
    convert_x<<<(nNodes * 16 + 255) / 256, 256, 0, stream>>>(nodes, Xb, nNodes * 16);
    hist<<<1024, 256, 0, stream>>>(edges, counts, nEdges);

    edge_mfma<<<(nEdges + 63) / 64, 256, 0, stream>>>(Xb, edges, ew, W1T, b1f, agg, nEdges);
    node_mfma<<<(nNodes + 63) / 64, 256, 0, stream>>>(Xb, agg, counts, W2T, b2f, out, nNodes);
}

// Round 3
// 362.822 us; speedup vs baseline: 3.0450x; 1.5142x over previous
//
#include <hip/hip_runtime.h>
#include <math.h>

#define F 128
#define TWO_F 256
#define BN_EPS 1e-5f
#define PAD_A 136    // 128+8 bf16: row stride -> 4-bank offset, 2-way (free)
#define PAD_A2 264   // 256+8 bf16

typedef unsigned short ushort_t;
typedef __attribute__((ext_vector_type(8))) short bfrag;   // 8 bf16
typedef __attribute__((ext_vector_type(4))) float ffrag;   // 4 fp32

__device__ __forceinline__ float gelu_exact(float x) {
    return 0.5f * x * (1.0f + erff(x * 0.70710678118654752f));
}
__device__ __forceinline__ ushort_t f2bf(float x) {
    unsigned int u = __float_as_uint(x);
    u = (u + 0x7FFFu + ((u >> 16) & 1u)) >> 16;
    return (ushort_t)u;
}
__device__ __forceinline__ unsigned int pk2(float a, float b) {
    return (unsigned int)f2bf(a) | ((unsigned int)f2bf(b) << 16);
}
__device__ __forceinline__ float bflo(unsigned int u) { return __uint_as_float(u << 16); }
__device__ __forceinline__ float bfhi(unsigned int u) { return __uint_as_float(u & 0xFFFF0000u); }

// ---------------- fold kernels ----------------
__global__ void fold_wT(const float* __restrict__ pre_w,
                        const float* __restrict__ g1, const float* __restrict__ v1,
                        const float* __restrict__ upd_w,
                        const float* __restrict__ g2, const float* __restrict__ v2,
                        ushort_t* __restrict__ W1T, ushort_t* __restrict__ W2T) {
    int idx = blockIdx.x * blockDim.x + threadIdx.x;
    if (idx < F * F) {
        int k = idx & (F - 1), n = idx >> 7;
        float s = g1[k] * rsqrtf(v1[k] + BN_EPS);
        W1T[idx] = f2bf(s * pre_w[k * F + n]);
    }
    if (idx < TWO_F * F) {
        int k = idx & (TWO_F - 1), n = idx >> 8;
        float s = g2[k] * rsqrtf(v2[k] + BN_EPS);
        W2T[idx] = f2bf(s * upd_w[k * F + n]);
    }
}

__global__ void fold_bias(const float* __restrict__ pre_w, const float* __restrict__ pre_b,
                          const float* __restrict__ pre_g, const float* __restrict__ pre_be,
                          const float* __restrict__ pre_m, const float* __restrict__ pre_v,
                          const float* __restrict__ upd_w, const float* __restrict__ upd_b,
                          const float* __restrict__ upd_g, const float* __restrict__ upd_be,
                          const float* __restrict__ upd_m, const float* __restrict__ upd_v,
                          float* __restrict__ b1f, float* __restrict__ b2f) {
    int tid = threadIdx.x;
    if (tid < F) {
        int j = tid;
        float acc = pre_b[j];
        for (int k = 0; k < F; ++k) {
            float s = pre_g[k] * rsqrtf(pre_v[k] + BN_EPS);
            float t = pre_be[k] - pre_m[k] * s;
            acc = fmaf(t, pre_w[k * F + j], acc);
        }
        b1f[j] = acc;
    } else {
        int j = tid - F;
        float acc = upd_b[j];
        for (int k = 0; k < TWO_F; ++k) {
            float s = upd_g[k] * rsqrtf(upd_v[k] + BN_EPS);
            float t = upd_be[k] - upd_m[k] * s;
            acc = fmaf(t, upd_w[k * F + j], acc);
        }
        b2f[j] = acc;
    }
}

__global__ void convert_x(const float* __restrict__ nodes, ushort_t* __restrict__ Xb, int n8) {
    int i = blockIdx.x * blockDim.x + threadIdx.x;
    if (i >= n8) return;
    const float4* s = reinterpret_cast<const float4*>(nodes) + 2 * (size_t)i;
    float4 a = s[0], b = s[1];
    uint4 p;
    p.x = pk2(a.x, a.y); p.y = pk2(a.z, a.w);
    p.z = pk2(b.x, b.y); p.w = pk2(b.z, b.w);
    reinterpret_cast<uint4*>(Xb)[i] = p;
}

// ---------------- CSR build ----------------
__global__ void hist(const int* __restrict__ edges, int* __restrict__ counts, int nEdges) {
    for (int i = blockIdx.x * blockDim.x + threadIdx.x; i < nEdges; i += gridDim.x * blockDim.x)
        atomicAdd(&counts[edges[i]], 1);
}

// pass 1: per-chunk inclusive scan (chunk = 1024), write chunk-local inclusive to offsets[idx+1]
__global__ __launch_bounds__(1024) void scan_pass1(const int* __restrict__ counts,
                                                   int* __restrict__ offsets,
                                                   int* __restrict__ blocksums, int n) {
    __shared__ int sb[1024];
    const int t = threadIdx.x;
    int idx = blockIdx.x * 1024 + t;
    int v = (idx < n) ? counts[idx] : 0;
    sb[t] = v;
    __syncthreads();
    for (int off = 1; off < 1024; off <<= 1) {
        int x = (t >= off) ? sb[t - off] : 0;
        __syncthreads();
        sb[t] += x;
        __syncthreads();
    }
    if (idx < n) offsets[idx + 1] = sb[t];
    if (t == 1023) blocksums[blockIdx.x] = sb[t];
}

// pass 2: exclusive scan of blocksums (nBlocks <= 1024), in one block
__global__ __launch_bounds__(1024) void scan_pass2(int* __restrict__ blocksums, int nBlocks,
                                                   int* __restrict__ offsets) {
    __shared__ int sb[1024];
    const int t = threadIdx.x;
    int v = (t < nBlocks) ? blocksums[t] : 0;
    sb[t] = v;
    __syncthreads();
    for (int off = 1; off < 1024; off <<= 1) {
        int x = (t >= off) ? sb[t - off] : 0;
        __syncthreads();
        sb[t] += x;
        __syncthreads();
    }
    if (t < nBlocks) blocksums[t] = sb[t] - v;  // exclusive
    if (t == 0) offsets[0] = 0;
}

// pass 3: add block base, derive cursor (exclusive offset per node)
__global__ __launch_bounds__(1024) void scan_pass3(const int* __restrict__ counts,
                                                   int* __restrict__ offsets,
                                                   const int* __restrict__ blocksums,
                                                   int* __restrict__ cursor, int n) {
    int idx = blockIdx.x * 1024 + threadIdx.x;
    if (idx < n) {
        int incl = offsets[idx + 1] + blocksums[blockIdx.x];
        offsets[idx + 1] = incl;
        cursor[idx] = incl - counts[idx];
    }
}

__global__ void fill_csr(const int* __restrict__ edges, const float* __restrict__ ew,
                         int* __restrict__ cursor, int* __restrict__ csr_nbr,
                         float* __restrict__ csr_ew, int nEdges) {
    for (int e = blockIdx.x * blockDim.x + threadIdx.x; e < nEdges; e += gridDim.x * blockDim.x) {
        int dst = edges[e];
        int pos = atomicAdd(&cursor[dst], 1);
        csr_nbr[pos] = edges[nEdges + e];
        csr_ew[pos] = ew[e];
    }
}

// ---------------- per-node FFN1: G = bf16(gelu(Xb @ W1T^T + b1)) ----------------
__global__ __launch_bounds__(256) void gemm1(const ushort_t* __restrict__ Xb,
                                             const ushort_t* __restrict__ W1T,
                                             const float* __restrict__ b1f,
                                             ushort_t* __restrict__ G, int nNodes) {
    __shared__ ushort_t As[64 * PAD_A];
    __shared__ float bs[F];
    const int t = threadIdx.x;
    const int base = blockIdx.x * 64;
    {
        int r = t >> 2, q = t & 3;
        int n = base + r;
        int sn = (n < nNodes) ? n : 0;
        const uint4* src = reinterpret_cast<const uint4*>(Xb + (size_t)sn * F + q * 32);
        uint4* dst = reinterpret_cast<uint4*>(As + r * PAD_A + q * 32);
        #pragma unroll
        for (int i = 0; i < 4; ++i) dst[i] = src[i];
    }
    if (t < F) bs[t] = b1f[t];
    __syncthreads();

    const int lane = t & 63, w = t >> 6;
    const int m = lane & 15, quad = lane >> 4;

    ffrag acc[8];
    #pragma unroll
    for (int c = 0; c < 8; ++c) acc[c] = (ffrag){0.f, 0.f, 0.f, 0.f};

    #pragma unroll
    for (int kk = 0; kk < 4; ++kk) {
        int k0 = kk * 32 + quad * 8;
        bfrag a = *reinterpret_cast<const bfrag*>(As + (w * 16 + m) * PAD_A + k0);
        #pragma unroll
        for (int c = 0; c < 8; ++c) {
            bfrag b = *reinterpret_cast<const bfrag*>(W1T + (size_t)(c * 16 + m) * F + k0);
            acc[c] = __builtin_amdgcn_mfma_f32_16x16x32_bf16(a, b, acc[c], 0, 0, 0);
        }
    }

    #pragma unroll
    for (int c = 0; c < 8; ++c) {
        int feat = c * 16 + m;
        float bj = bs[feat];
        #pragma unroll
        for (int i = 0; i < 4; ++i) {
            int n = base + w * 16 + quad * 4 + i;
            if (n < nNodes) G[(size_t)n * F + feat] = f2bf(gelu_exact(acc[c][i] + bj));
        }
    }
}

// ---------------- fused aggregation + FFN2 ----------------
// 64 nodes/block. A-tile = [Xb[n], bf16(sum_e ew*G[nbr] / (deg*F))]; out = gelu(A @ W2T^T + b2)
__global__ __launch_bounds__(256) void node_fused(
    const ushort_t* __restrict__ Xb, const ushort_t* __restrict__ G,
    const int* __restrict__ offsets, const int* __restrict__ csr_nbr,
    const float* __restrict__ csr_ew, const ushort_t* __restrict__ W2T,
    const float* __restrict__ b2f, float* __restrict__ out, int nNodes) {
    __shared__ ushort_t As[64 * PAD_A2];
    __shared__ float bs[F];
    const int t = threadIdx.x;
    const int base = blockIdx.x * 64;
    const int r = t >> 2, q = t & 3;

    // stage Xb half of the A-tile
    {
        int n = base + r;
        int sn = (n < nNodes) ? n : 0;
        const uint4* src = reinterpret_cast<const uint4*>(Xb + (size_t)sn * F + q * 32);
        uint4* dst = reinterpret_cast<uint4*>(As + r * PAD_A2 + q * 32);
        #pragma unroll
        for (int i = 0; i < 4; ++i) dst[i] = src[i];
    }

    // CSR gather: 4 threads per node, 32 feats each, fp32 accumulate
    {
        int n = base + r;
        float acc[32];
        #pragma unroll
        for (int j = 0; j < 32; ++j) acc[j] = 0.f;
        int s = 0, e = 0;
        if (n < nNodes) { s = offsets[n]; e = offsets[n + 1]; }
        for (int i = s; i < e; ++i) {
            int nbr = csr_nbr[i];
            float w = csr_ew[i];
            const uint4* gp = reinterpret_cast<const uint4*>(G + (size_t)nbr * F + q * 32);
            #pragma unroll
            for (int u = 0; u < 4; ++u) {
                uint4 g = gp[u];
                acc[u * 8 + 0] = fmaf(w, bflo(g.x), acc[u * 8 + 0]);
                acc[u * 8 + 1] = fmaf(w, bfhi(g.x), acc[u * 8 + 1]);
                acc[u * 8 + 2] = fmaf(w, bflo(g.y), acc[u * 8 + 2]);
                acc[u * 8 + 3] = fmaf(w, bfhi(g.y), acc[u * 8 + 3]);
                acc[u * 8 + 4] = fmaf(w, bflo(g.z), acc[u * 8 + 4]);
                acc[u * 8 + 5] = fmaf(w, bfhi(g.z), acc[u * 8 + 5]);
                acc[u * 8 + 6] = fmaf(w, bflo(g.w), acc[u * 8 + 6]);
                acc[u * 8 + 7] = fmaf(w, bfhi(g.w), acc[u * 8 + 7]);
            }
        }
        int deg = e - s;
        float inv = (deg > 0) ? 1.0f / ((float)deg * (float)F) : 0.f;  // counter = deg*F quirk
        unsigned int* dstu = reinterpret_cast<unsigned int*>(As + r * PAD_A2 + F + q * 32);
        #pragma unroll
        for (int j = 0; j < 16; ++j) dstu[j] = pk2(acc[2 * j] * inv, acc[2 * j + 1] * inv);
    }
    if (t < F) bs[t] = b2f[t];
    __syncthreads();

    const int lane = t & 63, w = t >> 6;
    const int m = lane & 15, quad = lane >> 4;

    ffrag acc[8];
    #pragma unroll
    for (int c = 0; c < 8; ++c) acc[c] = (ffrag){0.f, 0.f, 0.f, 0.f};

    #pragma unroll
    for (int kk = 0; kk < 8; ++kk) {
        int k0 = kk * 32 + quad * 8;
        bfrag a = *reinterpret_cast<const bfrag*>(As + (w * 16 + m) * PAD_A2 + k0);
        #pragma unroll
        for (int c = 0; c < 8; ++c) {
            bfrag b = *reinterpret_cast<const bfrag*>(W2T + (size_t)(c * 16 + m) * TWO_F + k0);
            acc[c] = __builtin_amdgcn_mfma_f32_16x16x32_bf16(a, b, acc[c], 0, 0, 0);
        }
    }

    #pragma unroll
    for (int c = 0; c < 8; ++c) {
        int feat = c * 16 + m;
        float bj = bs[feat];
        #pragma unroll
        for (int i = 0; i < 4; ++i) {
            int n = base + w * 16 + quad * 4 + i;
            if (n < nNodes) out[(size_t)n * F + feat] = gelu_exact(acc[c][i] + bj);
        }
    }
}

extern "C" void kernel_launch(void* const* d_in, const int* in_sizes, int n_in,
                              void* d_out, int out_size, void* d_ws, size_t ws_size,
                              hipStream_t stream) {
    const float* nodes  = (const float*)d_in[0];
    const int*   edges  = (const int*)d_in[1];
    const float* ew     = (const float*)d_in[2];
    const float* pre_g  = (const float*)d_in[3];
    const float* pre_be = (const float*)d_in[4];
    const float* pre_m  = (const float*)d_in[5];
    const float* pre_v  = (const float*)d_in[6];
    const float* pre_w  = (const float*)d_in[7];
    const float* pre_b  = (const float*)d_in[8];
    const float* upd_g  = (const float*)d_in[9];
    const float* upd_be = (const float*)d_in[10];
    const float* upd_m  = (const float*)d_in[11];
    const float* upd_v  = (const float*)d_in[12];
    const float* upd_w  = (const float*)d_in[13];
    const float* upd_b  = (const float*)d_in[14];
    float* out = (float*)d_out;

    const int nNodes = in_sizes[0] / F;
    const int nEdges = in_sizes[2];
    const int nChunks = (nNodes + 1023) / 1024;

    // ws layout (16B aligned blocks)
    char* p = (char*)d_ws;
    int*      counts    = (int*)p;       p += (size_t)nNodes * 4;
    int*      offsets   = (int*)p;       p += (size_t)(nNodes + 4) * 4;
    int*      cursor    = (int*)p;       p += (size_t)nNodes * 4;
    int*      blocksums = (int*)p;       p += 1024 * 4;
    int*      csr_nbr   = (int*)p;       p += (size_t)nEdges * 4;
    float*    csr_ew    = (float*)p;     p += (size_t)nEdges * 4;
    float*    b1f       = (float*)p;     p += F * 4;
    float*    b2f       = (float*)p;     p += F * 4;
    ushort_t* W1T       = (ushort_t*)p;  p += F * F * 2;
    ushort_t* W2T       = (ushort_t*)p;  p += TWO_F * F * 2;
    ushort_t* Xb        = (ushort_t*)p;  p += (size_t)nNodes * F * 2;
    ushort_t* G         = (ushort_t*)p;

    hipMemsetAsync(counts, 0, (size_t)nNodes * 4, stream);

    fold_wT<<<(TWO_F * F + 255) / 256, 256, 0, stream>>>(
        pre_w, pre_g, pre_v, upd_w, upd_g, upd_v, W1T, W2T);
    fold_bias<<<1, 256, 0, stream>>>(
        pre_w, pre_b, pre_g, pre_be, pre_m, pre_v,
        upd_w, upd_b, upd_g, upd_be, upd_m, upd_v, b1f, b2f);
    convert_x<<<(nNodes * 16 + 255) / 256, 256, 0, stream>>>(nodes, Xb, nNodes * 16);

    hist<<<1024, 256, 0, stream>>>(edges, counts, nEdges);
    scan_pass1<<<nChunks, 1024, 0, stream>>>(counts, offsets, blocksums, nNodes);
    scan_pass2<<<1, 1024, 0, stream>>>(blocksums, nChunks, offsets);
    scan_pass3<<<nChunks, 1024, 0, stream>>>(counts, offsets, blocksums, cursor, nNodes);
    fill_csr<<<1024, 256, 0, stream>>>(edges, ew, cursor, csr_nbr, csr_ew, nEdges);

    gemm1<<<(nNodes + 63) / 64, 256, 0, stream>>>(Xb, W1T, b1f, G, nNodes);
    node_fused<<<(nNodes + 63) / 64, 256, 0, stream>>>(
        Xb, G, offsets, csr_nbr, csr_ew, W2T, b2f, out, nNodes);
}

// Round 4
// 353.408 us; speedup vs baseline: 3.1261x; 1.0266x over previous
//
#include <hip/hip_runtime.h>
#include <math.h>

#define F 128
#define TWO_F 256
#define BN_EPS 1e-5f
#define PAD_A 136    // 128+8 bf16: row stride 272B -> bank offset 4, 2-way (free)
#define PAD_A2 264   // 256+8 bf16

typedef unsigned short ushort_t;
typedef __attribute__((ext_vector_type(8))) short bfrag;   // 8 bf16
typedef __attribute__((ext_vector_type(4))) float ffrag;   // 4 fp32

__device__ __forceinline__ float gelu_exact(float x) {
    return 0.5f * x * (1.0f + erff(x * 0.70710678118654752f));
}
__device__ __forceinline__ ushort_t f2bf(float x) {
    unsigned int u = __float_as_uint(x);
    u = (u + 0x7FFFu + ((u >> 16) & 1u)) >> 16;
    return (ushort_t)u;
}
__device__ __forceinline__ unsigned int pk2(float a, float b) {
    return (unsigned int)f2bf(a) | ((unsigned int)f2bf(b) << 16);
}
__device__ __forceinline__ float bflo(unsigned int u) { return __uint_as_float(u << 16); }
__device__ __forceinline__ float bfhi(unsigned int u) { return __uint_as_float(u & 0xFFFF0000u); }

__device__ __forceinline__ void acc8(float* acc, uint4 g, float w) {
    acc[0] = fmaf(w, bflo(g.x), acc[0]);
    acc[1] = fmaf(w, bfhi(g.x), acc[1]);
    acc[2] = fmaf(w, bflo(g.y), acc[2]);
    acc[3] = fmaf(w, bfhi(g.y), acc[3]);
    acc[4] = fmaf(w, bflo(g.z), acc[4]);
    acc[5] = fmaf(w, bfhi(g.z), acc[5]);
    acc[6] = fmaf(w, bflo(g.w), acc[6]);
    acc[7] = fmaf(w, bfhi(g.w), acc[7]);
}

// ---------------- merged param fold ----------------
// block 0: biases (threads 0-127 -> b1f, 128-255 -> b2f), t-vectors cached in LDS
// blocks 1..128: weight fold+transpose to bf16
__global__ __launch_bounds__(256) void fold_params(
    const float* __restrict__ pre_w, const float* __restrict__ pre_b,
    const float* __restrict__ g1, const float* __restrict__ be1,
    const float* __restrict__ m1, const float* __restrict__ v1,
    const float* __restrict__ upd_w, const float* __restrict__ upd_b,
    const float* __restrict__ g2, const float* __restrict__ be2,
    const float* __restrict__ m2, const float* __restrict__ v2,
    ushort_t* __restrict__ W1T, ushort_t* __restrict__ W2T,
    float* __restrict__ b1f, float* __restrict__ b2f) {
    const int t = threadIdx.x;
    if (blockIdx.x == 0) {
        __shared__ float t1[F], t2[TWO_F];
        if (t < F) {
            float s = g1[t] * rsqrtf(v1[t] + BN_EPS);
            t1[t] = be1[t] - m1[t] * s;
        }
        {
            float s = g2[t] * rsqrtf(v2[t] + BN_EPS);
            t2[t] = be2[t] - m2[t] * s;
        }
        __syncthreads();
        if (t < F) {
            float acc = pre_b[t];
            #pragma unroll 4
            for (int k = 0; k < F; ++k) acc = fmaf(t1[k], pre_w[k * F + t], acc);
            b1f[t] = acc;
        } else {
            int j = t - F;
            float acc = upd_b[j];
            #pragma unroll 4
            for (int k = 0; k < TWO_F; ++k) acc = fmaf(t2[k], upd_w[k * F + j], acc);
            b2f[j] = acc;
        }
    } else {
        int idx = (blockIdx.x - 1) * 256 + t;
        if (idx < F * F) {
            int k = idx & (F - 1), n = idx >> 7;
            float s = g1[k] * rsqrtf(v1[k] + BN_EPS);
            W1T[idx] = f2bf(s * pre_w[k * F + n]);
        }
        {
            int k = idx & (TWO_F - 1), n = idx >> 8;
            float s = g2[k] * rsqrtf(v2[k] + BN_EPS);
            W2T[idx] = f2bf(s * upd_w[k * F + n]);
        }
    }
}

// ---------------- CSR build ----------------
__global__ void hist(const int* __restrict__ edges, int* __restrict__ counts, int nEdges) {
    for (int i = blockIdx.x * blockDim.x + threadIdx.x; i < nEdges; i += gridDim.x * blockDim.x)
        atomicAdd(&counts[edges[i]], 1);
}

__global__ __launch_bounds__(1024) void scan_pass1(const int* __restrict__ counts,
                                                   int* __restrict__ offsets,
                                                   int* __restrict__ blocksums, int n) {
    __shared__ int sb[1024];
    const int t = threadIdx.x;
    int idx = blockIdx.x * 1024 + t;
    int v = (idx < n) ? counts[idx] : 0;
    sb[t] = v;
    __syncthreads();
    for (int off = 1; off < 1024; off <<= 1) {
        int x = (t >= off) ? sb[t - off] : 0;
        __syncthreads();
        sb[t] += x;
        __syncthreads();
    }
    if (idx < n) offsets[idx + 1] = sb[t];
    if (t == 1023) blocksums[blockIdx.x] = sb[t];
}

__global__ __launch_bounds__(1024) void scan_pass2(int* __restrict__ blocksums, int nBlocks,
                                                   int* __restrict__ offsets) {
    __shared__ int sb[1024];
    const int t = threadIdx.x;
    int v = (t < nBlocks) ? blocksums[t] : 0;
    sb[t] = v;
    __syncthreads();
    for (int off = 1; off < 1024; off <<= 1) {
        int x = (t >= off) ? sb[t - off] : 0;
        __syncthreads();
        sb[t] += x;
        __syncthreads();
    }
    if (t < nBlocks) blocksums[t] = sb[t] - v;  // exclusive
    if (t == 0) offsets[0] = 0;
}

__global__ __launch_bounds__(1024) void scan_pass3(const int* __restrict__ counts,
                                                   int* __restrict__ offsets,
                                                   const int* __restrict__ blocksums,
                                                   int* __restrict__ cursor, int n) {
    int idx = blockIdx.x * 1024 + threadIdx.x;
    if (idx < n) {
        int incl = offsets[idx + 1] + blocksums[blockIdx.x];
        offsets[idx + 1] = incl;
        cursor[idx] = incl - counts[idx];
    }
}

__global__ void fill_csr(const int* __restrict__ edges, const float* __restrict__ ew,
                         int* __restrict__ cursor, int* __restrict__ csr_nbr,
                         float* __restrict__ csr_ew, int nEdges) {
    for (int e = blockIdx.x * blockDim.x + threadIdx.x; e < nEdges; e += gridDim.x * blockDim.x) {
        int dst = edges[e];
        int pos = atomicAdd(&cursor[dst], 1);
        csr_nbr[pos] = edges[nEdges + e];
        csr_ew[pos] = ew[e];
    }
}

// ---------------- per-node FFN1 (reads fp32 nodes; emits Xb bf16 + G bf16) ----------------
__global__ __launch_bounds__(256) void gemm1(const float* __restrict__ nodes,
                                             const ushort_t* __restrict__ W1T,
                                             const float* __restrict__ b1f,
                                             ushort_t* __restrict__ Xb,
                                             ushort_t* __restrict__ G, int nNodes) {
    __shared__ ushort_t As[64 * PAD_A];
    __shared__ float bs[F];
    const int t = threadIdx.x;
    const int base = blockIdx.x * 64;
    {
        int r = t >> 2, q = t & 3;
        int n = base + r;
        int sn = (n < nNodes) ? n : 0;
        const float4* src = reinterpret_cast<const float4*>(nodes + (size_t)sn * F + q * 32);
        uint4 pv[4];
        #pragma unroll
        for (int i = 0; i < 4; ++i) {
            float4 a = src[2 * i], b = src[2 * i + 1];
            pv[i].x = pk2(a.x, a.y); pv[i].y = pk2(a.z, a.w);
            pv[i].z = pk2(b.x, b.y); pv[i].w = pk2(b.z, b.w);
        }
        uint4* dst = reinterpret_cast<uint4*>(As + r * PAD_A + q * 32);
        #pragma unroll
        for (int i = 0; i < 4; ++i) dst[i] = pv[i];
        if (n < nNodes) {
            uint4* gx = reinterpret_cast<uint4*>(Xb + (size_t)n * F + q * 32);
            #pragma unroll
            for (int i = 0; i < 4; ++i) gx[i] = pv[i];
        }
    }
    if (t < F) bs[t] = b1f[t];
    __syncthreads();

    const int lane = t & 63, w = t >> 6;
    const int m = lane & 15, quad = lane >> 4;

    ffrag acc[8];
    #pragma unroll
    for (int c = 0; c < 8; ++c) acc[c] = (ffrag){0.f, 0.f, 0.f, 0.f};

    #pragma unroll
    for (int kk = 0; kk < 4; ++kk) {
        int k0 = kk * 32 + quad * 8;
        bfrag a = *reinterpret_cast<const bfrag*>(As + (w * 16 + m) * PAD_A + k0);
        #pragma unroll
        for (int c = 0; c < 8; ++c) {
            bfrag b = *reinterpret_cast<const bfrag*>(W1T + (size_t)(c * 16 + m) * F + k0);
            acc[c] = __builtin_amdgcn_mfma_f32_16x16x32_bf16(a, b, acc[c], 0, 0, 0);
        }
    }

    #pragma unroll
    for (int c = 0; c < 8; ++c) {
        int feat = c * 16 + m;
        float bj = bs[feat];
        #pragma unroll
        for (int i = 0; i < 4; ++i) {
            int n = base + w * 16 + quad * 4 + i;
            if (n < nNodes) G[(size_t)n * F + feat] = f2bf(gelu_exact(acc[c][i] + bj));
        }
    }
}

// ---------------- fused aggregation + FFN2 ----------------
__global__ __launch_bounds__(256) void node_fused(
    const ushort_t* __restrict__ Xb, const ushort_t* __restrict__ G,
    const int* __restrict__ offsets, const int* __restrict__ csr_nbr,
    const float* __restrict__ csr_ew, const ushort_t* __restrict__ W2T,
    const float* __restrict__ b2f, float* __restrict__ out, int nNodes) {
    __shared__ ushort_t As[64 * PAD_A2];
    __shared__ float bs[F];
    const int t = threadIdx.x;
    const int base = blockIdx.x * 64;
    const int r = t >> 2, q = t & 3;

    if (t < F) bs[t] = b2f[t];

    // stage Xb half of the A-tile
    {
        int n = base + r;
        int sn = (n < nNodes) ? n : 0;
        const uint4* src = reinterpret_cast<const uint4*>(Xb + (size_t)sn * F + q * 32);
        uint4* dst = reinterpret_cast<uint4*>(As + r * PAD_A2 + q * 32);
        #pragma unroll
        for (int i = 0; i < 4; ++i) dst[i] = src[i];
    }

    // CSR gather: 4 threads per node, 32 feats each, unrolled x2 for MLP
    {
        int n = base + r;
        float acc[32];
        #pragma unroll
        for (int j = 0; j < 32; ++j) acc[j] = 0.f;
        int s = 0, e = 0;
        if (n < nNodes) { s = offsets[n]; e = offsets[n + 1]; }
        int i = s;
        for (; i + 1 < e; i += 2) {
            int nbr0 = csr_nbr[i], nbr1 = csr_nbr[i + 1];
            float w0 = csr_ew[i], w1 = csr_ew[i + 1];
            const uint4* g0 = reinterpret_cast<const uint4*>(G + (size_t)nbr0 * F + q * 32);
            const uint4* g1 = reinterpret_cast<const uint4*>(G + (size_t)nbr1 * F + q * 32);
            uint4 a0 = g0[0], a1 = g0[1], a2 = g0[2], a3 = g0[3];
            uint4 b0 = g1[0], b1 = g1[1], b2 = g1[2], b3 = g1[3];
            acc8(acc + 0,  a0, w0); acc8(acc + 8,  a1, w0);
            acc8(acc + 16, a2, w0); acc8(acc + 24, a3, w0);
            acc8(acc + 0,  b0, w1); acc8(acc + 8,  b1, w1);
            acc8(acc + 16, b2, w1); acc8(acc + 24, b3, w1);
        }
        if (i < e) {
            int nbr0 = csr_nbr[i];
            float w0 = csr_ew[i];
            const uint4* g0 = reinterpret_cast<const uint4*>(G + (size_t)nbr0 * F + q * 32);
            uint4 a0 = g0[0], a1 = g0[1], a2 = g0[2], a3 = g0[3];
            acc8(acc + 0,  a0, w0); acc8(acc + 8,  a1, w0);
            acc8(acc + 16, a2, w0); acc8(acc + 24, a3, w0);
        }
        int deg = e - s;
        float inv = (deg > 0) ? 1.0f / ((float)deg * (float)F) : 0.f;  // counter = deg*F quirk
        unsigned int* dstu = reinterpret_cast<unsigned int*>(As + r * PAD_A2 + F + q * 32);
        #pragma unroll
        for (int j = 0; j < 16; ++j) dstu[j] = pk2(acc[2 * j] * inv, acc[2 * j + 1] * inv);
    }
    __syncthreads();

    const int lane = t & 63, w = t >> 6;
    const int m = lane & 15, quad = lane >> 4;

    ffrag acc[8];
    #pragma unroll
    for (int c = 0; c < 8; ++c) acc[c] = (ffrag){0.f, 0.f, 0.f, 0.f};

    #pragma unroll
    for (int kk = 0; kk < 8; ++kk) {
        int k0 = kk * 32 + quad * 8;
        bfrag a = *reinterpret_cast<const bfrag*>(As + (w * 16 + m) * PAD_A2 + k0);
        #pragma unroll
        for (int c = 0; c < 8; ++c) {
            bfrag b = *reinterpret_cast<const bfrag*>(W2T + (size_t)(c * 16 + m) * TWO_F + k0);
            acc[c] = __builtin_amdgcn_mfma_f32_16x16x32_bf16(a, b, acc[c], 0, 0, 0);
        }
    }

    #pragma unroll
    for (int c = 0; c < 8; ++c) {
        int feat = c * 16 + m;
        float bj = bs[feat];
        #pragma unroll
        for (int i = 0; i < 4; ++i) {
            int n = base + w * 16 + quad * 4 + i;
            if (n < nNodes) out[(size_t)n * F + feat] = gelu_exact(acc[c][i] + bj);
        }
    }
}

extern "C" void kernel_launch(void* const* d_in, const int* in_sizes, int n_in,
                              void* d_out, int out_size, void* d_ws, size_t ws_size,
                              hipStream_t stream) {
    const float* nodes  = (const float*)d_in[0];
    const int*   edges  = (const int*)d_in[1];
    const float* ew     = (const float*)d_in[2];
    const float* pre_g  = (const float*)d_in[3];
    const float* pre_be = (const float*)d_in[4];
    const float* pre_m  = (const float*)d_in[5];
    const float* pre_v  = (const float*)d_in[6];
    const float* pre_w  = (const float*)d_in[7];
    const float* pre_b  = (const float*)d_in[8];
    const float* upd_g  = (const float*)d_in[9];
    const float* upd_be = (const float*)d_in[10];
    const float* upd_m  = (const float*)d_in[11];
    const float* upd_v  = (const float*)d_in[12];
    const float* upd_w  = (const float*)d_in[13];
    const float* upd_b  = (const float*)d_in[14];
    float* out = (float*)d_out;

    const int nNodes = in_sizes[0] / F;
    const int nEdges = in_sizes[2];
    const int nChunks = (nNodes + 1023) / 1024;

    // ws layout (16B aligned blocks)
    char* p = (char*)d_ws;
    int*      counts    = (int*)p;       p += (size_t)nNodes * 4;
    int*      offsets   = (int*)p;       p += (size_t)(nNodes + 4) * 4;
    int*      cursor    = (int*)p;       p += (size_t)nNodes * 4;
    int*      blocksums = (int*)p;       p += 1024 * 4;
    int*      csr_nbr   = (int*)p;       p += (size_t)nEdges * 4;
    float*    csr_ew    = (float*)p;     p += (size_t)nEdges * 4;
    float*    b1f       = (float*)p;     p += F * 4;
    float*    b2f       = (float*)p;     p += F * 4;
    ushort_t* W1T       = (ushort_t*)p;  p += F * F * 2;
    ushort_t* W2T       = (ushort_t*)p;  p += TWO_F * F * 2;
    ushort_t* Xb        = (ushort_t*)p;  p += (size_t)nNodes * F * 2;
    ushort_t* G         = (ushort_t*)p;

    hipMemsetAsync(counts, 0, (size_t)nNodes * 4, stream);

    fold_params<<<129, 256, 0, stream>>>(
        pre_w, pre_b, pre_g, pre_be, pre_m, pre_v,
        upd_w, upd_b, upd_g, upd_be, upd_m, upd_v,
        W1T, W2T, b1f, b2f);

    hist<<<1024, 256, 0, stream>>>(edges, counts, nEdges);
    scan_pass1<<<nChunks, 1024, 0, stream>>>(counts, offsets, blocksums, nNodes);
    scan_pass2<<<1, 1024, 0, stream>>>(blocksums, nChunks, offsets);
    scan_pass3<<<nChunks, 1024, 0, stream>>>(counts, offsets, blocksums, cursor, nNodes);
    fill_csr<<<1024, 256, 0, stream>>>(edges, ew, cursor, csr_nbr, csr_ew, nEdges);

    gemm1<<<(nNodes + 63) / 64, 256, 0, stream>>>(nodes, W1T, b1f, Xb, G, nNodes);
    node_fused<<<(nNodes + 63) / 64, 256, 0, stream>>>(
        Xb, G, offsets, csr_nbr, csr_ew, W2T, b2f, out, nNodes);
}

// Round 5
// 341.715 us; speedup vs baseline: 3.2331x; 1.0342x over previous
//
#include <hip/hip_runtime.h>
#include <math.h>

#define F 128
#define TWO_F 256
#define BN_EPS 1e-5f
#define PAD_A 136    // 128+8 bf16 row stride: bank offset 4, 2-way (free)
#define PAD_A2 264   // 256+8 bf16

typedef unsigned short ushort_t;
typedef unsigned char uchar_t;
typedef __attribute__((ext_vector_type(8))) short bfrag;   // 8 bf16
typedef __attribute__((ext_vector_type(4))) float ffrag;   // 4 fp32
typedef __attribute__((ext_vector_type(2))) float floatx2;

__device__ __forceinline__ float gelu_exact(float x) {
    return 0.5f * x * (1.0f + erff(x * 0.70710678118654752f));
}
__device__ __forceinline__ ushort_t f2bf(float x) {
    unsigned int u = __float_as_uint(x);
    u = (u + 0x7FFFu + ((u >> 16) & 1u)) >> 16;
    return (ushort_t)u;
}
__device__ __forceinline__ unsigned int pk2(float a, float b) {
    return (unsigned int)f2bf(a) | ((unsigned int)f2bf(b) << 16);
}

// 4 fp8 bytes in dword d -> 4 fp32, fma into acc[0..3] (byte order = feature order)
__device__ __forceinline__ void fma4_fp8(float* acc, unsigned int d, float w) {
    floatx2 lo = __builtin_amdgcn_cvt_pk_f32_fp8(d, false);
    floatx2 hi = __builtin_amdgcn_cvt_pk_f32_fp8(d, true);
    acc[0] = fmaf(w, lo.x, acc[0]);
    acc[1] = fmaf(w, lo.y, acc[1]);
    acc[2] = fmaf(w, hi.x, acc[2]);
    acc[3] = fmaf(w, hi.y, acc[3]);
}
__device__ __forceinline__ void fma32_fp8(float* acc, uint4 a, uint4 b, float w) {
    fma4_fp8(acc + 0,  a.x, w); fma4_fp8(acc + 4,  a.y, w);
    fma4_fp8(acc + 8,  a.z, w); fma4_fp8(acc + 12, a.w, w);
    fma4_fp8(acc + 16, b.x, w); fma4_fp8(acc + 20, b.y, w);
    fma4_fp8(acc + 24, b.z, w); fma4_fp8(acc + 28, b.w, w);
}

// ---------------- merged param fold ----------------
__global__ __launch_bounds__(256) void fold_params(
    const float* __restrict__ pre_w, const float* __restrict__ pre_b,
    const float* __restrict__ g1, const float* __restrict__ be1,
    const float* __restrict__ m1, const float* __restrict__ v1,
    const float* __restrict__ upd_w, const float* __restrict__ upd_b,
    const float* __restrict__ g2, const float* __restrict__ be2,
    const float* __restrict__ m2, const float* __restrict__ v2,
    ushort_t* __restrict__ W1T, ushort_t* __restrict__ W2T,
    float* __restrict__ b1f, float* __restrict__ b2f) {
    const int t = threadIdx.x;
    if (blockIdx.x == 0) {
        __shared__ float t1[F], t2[TWO_F];
        if (t < F) {
            float s = g1[t] * rsqrtf(v1[t] + BN_EPS);
            t1[t] = be1[t] - m1[t] * s;
        }
        {
            float s = g2[t] * rsqrtf(v2[t] + BN_EPS);
            t2[t] = be2[t] - m2[t] * s;
        }
        __syncthreads();
        if (t < F) {
            float acc = pre_b[t];
            #pragma unroll 4
            for (int k = 0; k < F; ++k) acc = fmaf(t1[k], pre_w[k * F + t], acc);
            b1f[t] = acc;
        } else {
            int j = t - F;
            float acc = upd_b[j];
            #pragma unroll 4
            for (int k = 0; k < TWO_F; ++k) acc = fmaf(t2[k], upd_w[k * F + j], acc);
            b2f[j] = acc;
        }
    } else {
        int idx = (blockIdx.x - 1) * 256 + t;
        if (idx < F * F) {
            int k = idx & (F - 1), n = idx >> 7;
            float s = g1[k] * rsqrtf(v1[k] + BN_EPS);
            W1T[idx] = f2bf(s * pre_w[k * F + n]);
        }
        {
            int k = idx & (TWO_F - 1), n = idx >> 8;
            float s = g2[k] * rsqrtf(v2[k] + BN_EPS);
            W2T[idx] = f2bf(s * upd_w[k * F + n]);
        }
    }
}

// ---------------- CSR build ----------------
__global__ void hist(const int* __restrict__ edges, int* __restrict__ counts, int nEdges) {
    for (int i = blockIdx.x * blockDim.x + threadIdx.x; i < nEdges; i += gridDim.x * blockDim.x)
        atomicAdd(&counts[edges[i]], 1);
}

__global__ __launch_bounds__(1024) void scan_pass1(const int* __restrict__ counts,
                                                   int* __restrict__ offsets,
                                                   int* __restrict__ blocksums, int n) {
    __shared__ int sb[1024];
    const int t = threadIdx.x;
    int idx = blockIdx.x * 1024 + t;
    int v = (idx < n) ? counts[idx] : 0;
    sb[t] = v;
    __syncthreads();
    for (int off = 1; off < 1024; off <<= 1) {
        int x = (t >= off) ? sb[t - off] : 0;
        __syncthreads();
        sb[t] += x;
        __syncthreads();
    }
    if (idx < n) offsets[idx + 1] = sb[t];
    if (t == 1023) blocksums[blockIdx.x] = sb[t];
}

// pass3: per-block redundant reduce of blocksums -> base, then finalize offsets + cursor
__global__ __launch_bounds__(1024) void scan_pass3(const int* __restrict__ counts,
                                                   int* __restrict__ offsets,
                                                   const int* __restrict__ blocksums,
                                                   int* __restrict__ cursor, int n) {
    __shared__ int sb[1024];
    const int t = threadIdx.x;
    sb[t] = (t < blockIdx.x) ? blocksums[t] : 0;   // blockIdx < nChunks <= 1024
    __syncthreads();
    #pragma unroll
    for (int off = 512; off > 0; off >>= 1) {
        if (t < off) sb[t] += sb[t + off];
        __syncthreads();
    }
    int base = sb[0];
    int idx = blockIdx.x * 1024 + t;
    if (idx < n) {
        int incl = offsets[idx + 1] + base;
        offsets[idx + 1] = incl;
        cursor[idx] = incl - counts[idx];
    }
    if (blockIdx.x == 0 && t == 0) offsets[0] = 0;
}

__global__ void fill_csr(const int* __restrict__ edges, const float* __restrict__ ew,
                         int* __restrict__ cursor, int2* __restrict__ csr, int nEdges) {
    for (int e = blockIdx.x * blockDim.x + threadIdx.x; e < nEdges; e += gridDim.x * blockDim.x) {
        int dst = edges[e];
        int pos = atomicAdd(&cursor[dst], 1);
        csr[pos] = make_int2(edges[nEdges + e], __float_as_int(ew[e]));
    }
}

// ---------------- per-node FFN1: G8 = fp8(gelu(X @ W1T^T + b1)) ----------------
__global__ __launch_bounds__(256) void gemm1(const float* __restrict__ nodes,
                                             const ushort_t* __restrict__ W1T,
                                             const float* __restrict__ b1f,
                                             uchar_t* __restrict__ G8, int nNodes) {
    __shared__ ushort_t As[64 * PAD_A];
    __shared__ float bs[F];
    const int t = threadIdx.x;
    const int base = blockIdx.x * 64;
    {
        int r = t >> 2, q = t & 3;
        int n = base + r;
        int sn = (n < nNodes) ? n : 0;
        const float4* src = reinterpret_cast<const float4*>(nodes + (size_t)sn * F + q * 32);
        uint4 pv[4];
        #pragma unroll
        for (int i = 0; i < 4; ++i) {
            float4 a = src[2 * i], b = src[2 * i + 1];
            pv[i].x = pk2(a.x, a.y); pv[i].y = pk2(a.z, a.w);
            pv[i].z = pk2(b.x, b.y); pv[i].w = pk2(b.z, b.w);
        }
        uint4* dst = reinterpret_cast<uint4*>(As + r * PAD_A + q * 32);
        #pragma unroll
        for (int i = 0; i < 4; ++i) dst[i] = pv[i];
    }
    if (t < F) bs[t] = b1f[t];
    __syncthreads();

    const int lane = t & 63, w = t >> 6;
    const int m = lane & 15, quad = lane >> 4;

    ffrag acc[8];
    #pragma unroll
    for (int c = 0; c < 8; ++c) acc[c] = (ffrag){0.f, 0.f, 0.f, 0.f};

    #pragma unroll
    for (int kk = 0; kk < 4; ++kk) {
        int k0 = kk * 32 + quad * 8;
        bfrag a = *reinterpret_cast<const bfrag*>(As + (w * 16 + m) * PAD_A + k0);
        #pragma unroll
        for (int c = 0; c < 8; ++c) {
            bfrag b = *reinterpret_cast<const bfrag*>(W1T + (size_t)(c * 16 + m) * F + k0);
            acc[c] = __builtin_amdgcn_mfma_f32_16x16x32_bf16(a, b, acc[c], 0, 0, 0);
        }
    }

    #pragma unroll
    for (int c = 0; c < 8; ++c) {
        int feat = c * 16 + m;
        float bj = bs[feat];
        #pragma unroll
        for (int i = 0; i < 4; ++i) {
            int n = base + w * 16 + quad * 4 + i;
            if (n < nNodes) {
                float v = gelu_exact(acc[c][i] + bj);
                int pkd = __builtin_amdgcn_cvt_pk_fp8_f32(v, v, 0, false);
                G8[(size_t)n * F + feat] = (uchar_t)(pkd & 0xFF);
            }
        }
    }
}

// ---------------- fused aggregation + FFN2 ----------------
__global__ __launch_bounds__(256) void node_fused(
    const float* __restrict__ nodes, const uchar_t* __restrict__ G8,
    const int* __restrict__ offsets, const int2* __restrict__ csr,
    const ushort_t* __restrict__ W2T, const float* __restrict__ b2f,
    float* __restrict__ out, int nNodes) {
    __shared__ ushort_t As[64 * PAD_A2];
    __shared__ float bs[F];
    const int t = threadIdx.x;
    const int base = blockIdx.x * 64;
    const int r = t >> 2, q = t & 3;

    if (t < F) bs[t] = b2f[t];

    // stage fp32 node row half (convert to bf16)
    {
        int n = base + r;
        int sn = (n < nNodes) ? n : 0;
        const float4* src = reinterpret_cast<const float4*>(nodes + (size_t)sn * F + q * 32);
        uint4 pv[4];
        #pragma unroll
        for (int i = 0; i < 4; ++i) {
            float4 a = src[2 * i], b = src[2 * i + 1];
            pv[i].x = pk2(a.x, a.y); pv[i].y = pk2(a.z, a.w);
            pv[i].z = pk2(b.x, b.y); pv[i].w = pk2(b.z, b.w);
        }
        uint4* dst = reinterpret_cast<uint4*>(As + r * PAD_A2 + q * 32);
        #pragma unroll
        for (int i = 0; i < 4; ++i) dst[i] = pv[i];
    }

    // CSR gather: 4 threads/node, 32 feats each, fp8 G rows (128B = 1 line), unroll x4
    {
        int n = base + r;
        float acc[32];
        #pragma unroll
        for (int j = 0; j < 32; ++j) acc[j] = 0.f;
        int s = 0, e = 0;
        if (n < nNodes) { s = offsets[n]; e = offsets[n + 1]; }
        int i = s;
        for (; i + 3 < e; i += 4) {
            int2 m0 = csr[i], m1 = csr[i + 1], m2 = csr[i + 2], m3 = csr[i + 3];
            const uint4* g0 = reinterpret_cast<const uint4*>(G8 + (size_t)m0.x * F + q * 32);
            const uint4* g1 = reinterpret_cast<const uint4*>(G8 + (size_t)m1.x * F + q * 32);
            const uint4* g2 = reinterpret_cast<const uint4*>(G8 + (size_t)m2.x * F + q * 32);
            const uint4* g3 = reinterpret_cast<const uint4*>(G8 + (size_t)m3.x * F + q * 32);
            uint4 a0 = g0[0], b0 = g0[1];
            uint4 a1 = g1[0], b1 = g1[1];
            uint4 a2 = g2[0], b2 = g2[1];
            uint4 a3 = g3[0], b3 = g3[1];
            fma32_fp8(acc, a0, b0, __int_as_float(m0.y));
            fma32_fp8(acc, a1, b1, __int_as_float(m1.y));
            fma32_fp8(acc, a2, b2, __int_as_float(m2.y));
            fma32_fp8(acc, a3, b3, __int_as_float(m3.y));
        }
        for (; i < e; ++i) {
            int2 m0 = csr[i];
            const uint4* g0 = reinterpret_cast<const uint4*>(G8 + (size_t)m0.x * F + q * 32);
            uint4 a0 = g0[0], b0 = g0[1];
            fma32_fp8(acc, a0, b0, __int_as_float(m0.y));
        }
        int deg = e - s;
        float inv = (deg > 0) ? 1.0f / ((float)deg * (float)F) : 0.f;  // counter = deg*F quirk
        unsigned int* dstu = reinterpret_cast<unsigned int*>(As + r * PAD_A2 + F + q * 32);
        #pragma unroll
        for (int j = 0; j < 16; ++j) dstu[j] = pk2(acc[2 * j] * inv, acc[2 * j + 1] * inv);
    }
    __syncthreads();

    const int lane = t & 63, w = t >> 6;
    const int m = lane & 15, quad = lane >> 4;

    ffrag acc[8];
    #pragma unroll
    for (int c = 0; c < 8; ++c) acc[c] = (ffrag){0.f, 0.f, 0.f, 0.f};

    #pragma unroll
    for (int kk = 0; kk < 8; ++kk) {
        int k0 = kk * 32 + quad * 8;
        bfrag a = *reinterpret_cast<const bfrag*>(As + (w * 16 + m) * PAD_A2 + k0);
        #pragma unroll
        for (int c = 0; c < 8; ++c) {
            bfrag b = *reinterpret_cast<const bfrag*>(W2T + (size_t)(c * 16 + m) * TWO_F + k0);
            acc[c] = __builtin_amdgcn_mfma_f32_16x16x32_bf16(a, b, acc[c], 0, 0, 0);
        }
    }

    #pragma unroll
    for (int c = 0; c < 8; ++c) {
        int feat = c * 16 + m;
        float bj = bs[feat];
        #pragma unroll
        for (int i = 0; i < 4; ++i) {
            int n = base + w * 16 + quad * 4 + i;
            if (n < nNodes) out[(size_t)n * F + feat] = gelu_exact(acc[c][i] + bj);
        }
    }
}

extern "C" void kernel_launch(void* const* d_in, const int* in_sizes, int n_in,
                              void* d_out, int out_size, void* d_ws, size_t ws_size,
                              hipStream_t stream) {
    const float* nodes  = (const float*)d_in[0];
    const int*   edges  = (const int*)d_in[1];
    const float* ew     = (const float*)d_in[2];
    const float* pre_g  = (const float*)d_in[3];
    const float* pre_be = (const float*)d_in[4];
    const float* pre_m  = (const float*)d_in[5];
    const float* pre_v  = (const float*)d_in[6];
    const float* pre_w  = (const float*)d_in[7];
    const float* pre_b  = (const float*)d_in[8];
    const float* upd_g  = (const float*)d_in[9];
    const float* upd_be = (const float*)d_in[10];
    const float* upd_m  = (const float*)d_in[11];
    const float* upd_v  = (const float*)d_in[12];
    const float* upd_w  = (const float*)d_in[13];
    const float* upd_b  = (const float*)d_in[14];
    float* out = (float*)d_out;

    const int nNodes = in_sizes[0] / F;
    const int nEdges = in_sizes[2];
    const int nChunks = (nNodes + 1023) / 1024;

    // ws layout (16B aligned blocks)
    char* p = (char*)d_ws;
    int*      counts    = (int*)p;       p += (size_t)nNodes * 4;
    int*      offsets   = (int*)p;       p += (size_t)(nNodes + 4) * 4;
    int*      cursor    = (int*)p;       p += (size_t)nNodes * 4;
    int*      blocksums = (int*)p;       p += 1024 * 4;
    int2*     csr       = (int2*)p;      p += (size_t)nEdges * 8;
    float*    b1f       = (float*)p;     p += F * 4;
    float*    b2f       = (float*)p;     p += F * 4;
    ushort_t* W1T       = (ushort_t*)p;  p += F * F * 2;
    ushort_t* W2T       = (ushort_t*)p;  p += TWO_F * F * 2;
    uchar_t*  G8        = (uchar_t*)p;

    hipMemsetAsync(counts, 0, (size_t)nNodes * 4, stream);

    fold_params<<<129, 256, 0, stream>>>(
        pre_w, pre_b, pre_g, pre_be, pre_m, pre_v,
        upd_w, upd_b, upd_g, upd_be, upd_m, upd_v,
        W1T, W2T, b1f, b2f);

    hist<<<1024, 256, 0, stream>>>(edges, counts, nEdges);
    scan_pass1<<<nChunks, 1024, 0, stream>>>(counts, offsets, blocksums, nNodes);
    scan_pass3<<<nChunks, 1024, 0, stream>>>(counts, offsets, blocksums, cursor, nNodes);
    fill_csr<<<1024, 256, 0, stream>>>(edges, ew, cursor, csr, nEdges);

    gemm1<<<(nNodes + 63) / 64, 256, 0, stream>>>(nodes, W1T, b1f, G8, nNodes);
    node_fused<<<(nNodes + 63) / 64, 256, 0, stream>>>(
        nodes, G8, offsets, csr, W2T, b2f, out, nNodes);
}

// Round 6
// 294.934 us; speedup vs baseline: 3.7459x; 1.1586x over previous
//
#include <hip/hip_runtime.h>
#include <math.h>

#define F 128
#define TWO_F 256
#define BN_EPS 1e-5f
#define PAD_A 136    // 128+8 bf16 row stride (gemm1 tile)
#define PAD_A2 264   // 256+8 bf16 row stride (node_fused tile)

typedef unsigned short ushort_t;
typedef unsigned char uchar_t;
typedef __attribute__((ext_vector_type(8))) short bfrag;   // 8 bf16
typedef __attribute__((ext_vector_type(4))) float ffrag;   // 4 fp32
typedef __attribute__((ext_vector_type(2))) float floatx2;

__device__ __forceinline__ float gelu_exact(float x) {
    return 0.5f * x * (1.0f + erff(x * 0.70710678118654752f));
}
__device__ __forceinline__ ushort_t f2bf(float x) {
    unsigned int u = __float_as_uint(x);
    u = (u + 0x7FFFu + ((u >> 16) & 1u)) >> 16;
    return (ushort_t)u;
}
__device__ __forceinline__ unsigned int pk2(float a, float b) {
    return (unsigned int)f2bf(a) | ((unsigned int)f2bf(b) << 16);
}

__device__ __forceinline__ void fma4_fp8(float* acc, unsigned int d, float w) {
    floatx2 lo = __builtin_amdgcn_cvt_pk_f32_fp8(d, false);
    floatx2 hi = __builtin_amdgcn_cvt_pk_f32_fp8(d, true);
    acc[0] = fmaf(w, lo.x, acc[0]);
    acc[1] = fmaf(w, lo.y, acc[1]);
    acc[2] = fmaf(w, hi.x, acc[2]);
    acc[3] = fmaf(w, hi.y, acc[3]);
}
__device__ __forceinline__ void fma16_fp8(float* acc, uint4 a, float w) {
    fma4_fp8(acc + 0,  a.x, w); fma4_fp8(acc + 4,  a.y, w);
    fma4_fp8(acc + 8,  a.z, w); fma4_fp8(acc + 12, a.w, w);
}

// ---------------- prep: param fold (blocks 0..128) + degree histogram (blocks 129+) ----------------
__global__ __launch_bounds__(256) void prep(
    const float* __restrict__ pre_w, const float* __restrict__ pre_b,
    const float* __restrict__ g1, const float* __restrict__ be1,
    const float* __restrict__ m1, const float* __restrict__ v1,
    const float* __restrict__ upd_w, const float* __restrict__ upd_b,
    const float* __restrict__ g2, const float* __restrict__ be2,
    const float* __restrict__ m2, const float* __restrict__ v2,
    ushort_t* __restrict__ W1T, ushort_t* __restrict__ W2T,
    float* __restrict__ b1f, float* __restrict__ b2f,
    const int* __restrict__ edges, int* __restrict__ counts, int nEdges, int histBlocks) {
    const int t = threadIdx.x;
    if (blockIdx.x == 0) {
        __shared__ float t1[F], t2[TWO_F];
        if (t < F) {
            float s = g1[t] * rsqrtf(v1[t] + BN_EPS);
            t1[t] = be1[t] - m1[t] * s;
        }
        {
            float s = g2[t] * rsqrtf(v2[t] + BN_EPS);
            t2[t] = be2[t] - m2[t] * s;
        }
        __syncthreads();
        if (t < F) {
            float acc = pre_b[t];
            #pragma unroll 4
            for (int k = 0; k < F; ++k) acc = fmaf(t1[k], pre_w[k * F + t], acc);
            b1f[t] = acc;
        } else {
            int j = t - F;
            float acc = upd_b[j];
            #pragma unroll 4
            for (int k = 0; k < TWO_F; ++k) acc = fmaf(t2[k], upd_w[k * F + j], acc);
            b2f[j] = acc;
        }
    } else if (blockIdx.x <= 128) {
        int idx = (blockIdx.x - 1) * 256 + t;
        if (idx < F * F) {
            int k = idx & (F - 1), n = idx >> 7;
            float s = g1[k] * rsqrtf(v1[k] + BN_EPS);
            W1T[idx] = f2bf(s * pre_w[k * F + n]);
        }
        {
            int k = idx & (TWO_F - 1), n = idx >> 8;
            float s = g2[k] * rsqrtf(v2[k] + BN_EPS);
            W2T[idx] = f2bf(s * upd_w[k * F + n]);
        }
    } else {
        int b = blockIdx.x - 129;
        for (int i = b * 256 + t; i < nEdges; i += histBlocks * 256)
            atomicAdd(&counts[edges[i]], 1);
    }
}

// ---------------- CSR scans ----------------
__global__ __launch_bounds__(1024) void scan_pass1(const int* __restrict__ counts,
                                                   int* __restrict__ offsets,
                                                   int* __restrict__ blocksums, int n) {
    __shared__ int sb[1024];
    const int t = threadIdx.x;
    int idx = blockIdx.x * 1024 + t;
    int v = (idx < n) ? counts[idx] : 0;
    sb[t] = v;
    __syncthreads();
    for (int off = 1; off < 1024; off <<= 1) {
        int x = (t >= off) ? sb[t - off] : 0;
        __syncthreads();
        sb[t] += x;
        __syncthreads();
    }
    if (idx < n) offsets[idx + 1] = sb[t];
    if (t == 1023) blocksums[blockIdx.x] = sb[t];
}

__global__ __launch_bounds__(1024) void scan_pass3(const int* __restrict__ counts,
                                                   int* __restrict__ offsets,
                                                   const int* __restrict__ blocksums,
                                                   int* __restrict__ cursor, int n) {
    __shared__ int sb[1024];
    const int t = threadIdx.x;
    sb[t] = (t < blockIdx.x) ? blocksums[t] : 0;
    __syncthreads();
    #pragma unroll
    for (int off = 512; off > 0; off >>= 1) {
        if (t < off) sb[t] += sb[t + off];
        __syncthreads();
    }
    int base = sb[0];
    int idx = blockIdx.x * 1024 + t;
    if (idx < n) {
        int incl = offsets[idx + 1] + base;
        offsets[idx + 1] = incl;
        cursor[idx] = incl - counts[idx];
    }
    if (blockIdx.x == 0 && t == 0) offsets[0] = 0;
}

// ---------------- gemm1 (blocks 0..gB-1) + fill_csr (blocks gB+) ----------------
__global__ __launch_bounds__(256) void gemm1_fill(
    const float* __restrict__ nodes, const ushort_t* __restrict__ W1T,
    const float* __restrict__ b1f, uchar_t* __restrict__ G8, int nNodes,
    const int* __restrict__ edges, const float* __restrict__ ew,
    int* __restrict__ cursor, int2* __restrict__ csr, int nEdges,
    int gB, int fillBlocks) {
    __shared__ ushort_t As[64 * PAD_A];
    __shared__ float bs[F];
    const int t = threadIdx.x;

    if (blockIdx.x >= gB) {   // fill_csr part
        int b = blockIdx.x - gB;
        for (int e = b * 256 + t; e < nEdges; e += fillBlocks * 256) {
            int dst = edges[e];
            int pos = atomicAdd(&cursor[dst], 1);
            csr[pos] = make_int2(edges[nEdges + e], __float_as_int(ew[e]));
        }
        return;
    }

    const int base = blockIdx.x * 64;
    {
        int r = t >> 2, q = t & 3;
        int n = base + r;
        int sn = (n < nNodes) ? n : 0;
        const float4* src = reinterpret_cast<const float4*>(nodes + (size_t)sn * F + q * 32);
        uint4 pv[4];
        #pragma unroll
        for (int i = 0; i < 4; ++i) {
            float4 a = src[2 * i], b = src[2 * i + 1];
            pv[i].x = pk2(a.x, a.y); pv[i].y = pk2(a.z, a.w);
            pv[i].z = pk2(b.x, b.y); pv[i].w = pk2(b.z, b.w);
        }
        uint4* dst = reinterpret_cast<uint4*>(As + r * PAD_A + q * 32);
        #pragma unroll
        for (int i = 0; i < 4; ++i) dst[i] = pv[i];
    }
    if (t < F) bs[t] = b1f[t];
    __syncthreads();

    const int lane = t & 63, w = t >> 6;
    const int m = lane & 15, quad = lane >> 4;

    ffrag acc[8];
    #pragma unroll
    for (int c = 0; c < 8; ++c) acc[c] = (ffrag){0.f, 0.f, 0.f, 0.f};

    #pragma unroll
    for (int kk = 0; kk < 4; ++kk) {
        int k0 = kk * 32 + quad * 8;
        bfrag a = *reinterpret_cast<const bfrag*>(As + (w * 16 + m) * PAD_A + k0);
        #pragma unroll
        for (int c = 0; c < 8; ++c) {
            bfrag b = *reinterpret_cast<const bfrag*>(W1T + (size_t)(c * 16 + m) * F + k0);
            acc[c] = __builtin_amdgcn_mfma_f32_16x16x32_bf16(a, b, acc[c], 0, 0, 0);
        }
    }

    #pragma unroll
    for (int c = 0; c < 8; ++c) {
        int feat = c * 16 + m;
        float bj = bs[feat];
        #pragma unroll
        for (int i = 0; i < 4; ++i) {
            int n = base + w * 16 + quad * 4 + i;
            if (n < nNodes) {
                float v = gelu_exact(acc[c][i] + bj);
                int pkd = __builtin_amdgcn_cvt_pk_fp8_f32(v, v, 0, false);
                G8[(size_t)n * F + feat] = (uchar_t)(pkd & 0xFF);
            }
        }
    }
}

// ---------------- fused aggregation + FFN2: 32 nodes/block, 8 threads/node ----------------
__global__ __launch_bounds__(256) void node_fused(
    const float* __restrict__ nodes, const uchar_t* __restrict__ G8,
    const int* __restrict__ offsets, const int2* __restrict__ csr,
    const ushort_t* __restrict__ W2T, const float* __restrict__ b2f,
    float* __restrict__ out, int nNodes) {
    __shared__ ushort_t As[32 * PAD_A2];   // ~16.9 KB
    __shared__ float bs[F];
    const int t = threadIdx.x;
    const int base = blockIdx.x * 32;
    const int r = t >> 3, q = t & 7;       // r: node slot 0..31, q: feat octant (16 feats)

    if (t < F) bs[t] = b2f[t];

    // stage fp32 node row half (16 feats/thread -> bf16)
    {
        int n = base + r;
        int sn = (n < nNodes) ? n : 0;
        const float4* src = reinterpret_cast<const float4*>(nodes + (size_t)sn * F + q * 16);
        uint4 pv[2];
        #pragma unroll
        for (int i = 0; i < 2; ++i) {
            float4 a = src[2 * i], b = src[2 * i + 1];
            pv[i].x = pk2(a.x, a.y); pv[i].y = pk2(a.z, a.w);
            pv[i].z = pk2(b.x, b.y); pv[i].w = pk2(b.z, b.w);
        }
        uint4* dst = reinterpret_cast<uint4*>(As + r * PAD_A2 + q * 16);
        dst[0] = pv[0]; dst[1] = pv[1];
    }

    // CSR gather: 8 threads/node, 16 fp8 feats each (one 16B load per edge), unroll x4
    {
        int n = base + r;
        float acc[16];
        #pragma unroll
        for (int j = 0; j < 16; ++j) acc[j] = 0.f;
        int s = 0, e = 0;
        if (n < nNodes) { s = offsets[n]; e = offsets[n + 1]; }
        int i = s;
        for (; i + 3 < e; i += 4) {
            int2 m0 = csr[i], m1 = csr[i + 1], m2 = csr[i + 2], m3 = csr[i + 3];
            uint4 a0 = *reinterpret_cast<const uint4*>(G8 + (size_t)m0.x * F + q * 16);
            uint4 a1 = *reinterpret_cast<const uint4*>(G8 + (size_t)m1.x * F + q * 16);
            uint4 a2 = *reinterpret_cast<const uint4*>(G8 + (size_t)m2.x * F + q * 16);
            uint4 a3 = *reinterpret_cast<const uint4*>(G8 + (size_t)m3.x * F + q * 16);
            fma16_fp8(acc, a0, __int_as_float(m0.y));
            fma16_fp8(acc, a1, __int_as_float(m1.y));
            fma16_fp8(acc, a2, __int_as_float(m2.y));
            fma16_fp8(acc, a3, __int_as_float(m3.y));
        }
        for (; i < e; ++i) {
            int2 m0 = csr[i];
            uint4 a0 = *reinterpret_cast<const uint4*>(G8 + (size_t)m0.x * F + q * 16);
            fma16_fp8(acc, a0, __int_as_float(m0.y));
        }
        int deg = e - s;
        float inv = (deg > 0) ? 1.0f / ((float)deg * (float)F) : 0.f;  // counter = deg*F quirk
        unsigned int* dstu = reinterpret_cast<unsigned int*>(As + r * PAD_A2 + F + q * 16);
        #pragma unroll
        for (int j = 0; j < 8; ++j) dstu[j] = pk2(acc[2 * j] * inv, acc[2 * j + 1] * inv);
    }
    __syncthreads();

    // MFMA: 4 waves = 2 row-groups x 2 col-groups; each wave 16 rows x 64 cols
    const int lane = t & 63, w = t >> 6;
    const int m = lane & 15, quad = lane >> 4;
    const int rg = w & 1, cg = w >> 1;

    ffrag acc[4];
    #pragma unroll
    for (int c = 0; c < 4; ++c) acc[c] = (ffrag){0.f, 0.f, 0.f, 0.f};

    #pragma unroll
    for (int kk = 0; kk < 8; ++kk) {
        int k0 = kk * 32 + quad * 8;
        bfrag a = *reinterpret_cast<const bfrag*>(As + (rg * 16 + m) * PAD_A2 + k0);
        #pragma unroll
        for (int c = 0; c < 4; ++c) {
            int feat = cg * 64 + c * 16 + m;
            bfrag b = *reinterpret_cast<const bfrag*>(W2T + (size_t)feat * TWO_F + k0);
            acc[c] = __builtin_amdgcn_mfma_f32_16x16x32_bf16(a, b, acc[c], 0, 0, 0);
        }
    }

    #pragma unroll
    for (int c = 0; c < 4; ++c) {
        int feat = cg * 64 + c * 16 + m;
        float bj = bs[feat];
        #pragma unroll
        for (int i = 0; i < 4; ++i) {
            int n = base + rg * 16 + quad * 4 + i;
            if (n < nNodes) out[(size_t)n * F + feat] = gelu_exact(acc[c][i] + bj);
        }
    }
}

extern "C" void kernel_launch(void* const* d_in, const int* in_sizes, int n_in,
                              void* d_out, int out_size, void* d_ws, size_t ws_size,
                              hipStream_t stream) {
    const float* nodes  = (const float*)d_in[0];
    const int*   edges  = (const int*)d_in[1];
    const float* ew     = (const float*)d_in[2];
    const float* pre_g  = (const float*)d_in[3];
    const float* pre_be = (const float*)d_in[4];
    const float* pre_m  = (const float*)d_in[5];
    const float* pre_v  = (const float*)d_in[6];
    const float* pre_w  = (const float*)d_in[7];
    const float* pre_b  = (const float*)d_in[8];
    const float* upd_g  = (const float*)d_in[9];
    const float* upd_be = (const float*)d_in[10];
    const float* upd_m  = (const float*)d_in[11];
    const float* upd_v  = (const float*)d_in[12];
    const float* upd_w  = (const float*)d_in[13];
    const float* upd_b  = (const float*)d_in[14];
    float* out = (float*)d_out;

    const int nNodes = in_sizes[0] / F;
    const int nEdges = in_sizes[2];
    const int nChunks = (nNodes + 1023) / 1024;
    const int histBlocks = 1024;
    const int gB = (nNodes + 63) / 64;
    const int fillBlocks = 1024;

    // ws layout (16B aligned blocks)
    char* p = (char*)d_ws;
    int*      counts    = (int*)p;       p += (size_t)nNodes * 4;
    int*      offsets   = (int*)p;       p += (size_t)(nNodes + 4) * 4;
    int*      cursor    = (int*)p;       p += (size_t)nNodes * 4;
    int*      blocksums = (int*)p;       p += 1024 * 4;
    int2*     csr       = (int2*)p;      p += (size_t)nEdges * 8;
    float*    b1f       = (float*)p;     p += F * 4;
    float*    b2f       = (float*)p;     p += F * 4;
    ushort_t* W1T       = (ushort_t*)p;  p += F * F * 2;
    ushort_t* W2T       = (ushort_t*)p;  p += TWO_F * F * 2;
    uchar_t*  G8        = (uchar_t*)p;

    hipMemsetAsync(counts, 0, (size_t)nNodes * 4, stream);

    prep<<<129 + histBlocks, 256, 0, stream>>>(
        pre_w, pre_b, pre_g, pre_be, pre_m, pre_v,
        upd_w, upd_b, upd_g, upd_be, upd_m, upd_v,
        W1T, W2T, b1f, b2f, edges, counts, nEdges, histBlocks);

    scan_pass1<<<nChunks, 1024, 0, stream>>>(counts, offsets, blocksums, nNodes);
    scan_pass3<<<nChunks, 1024, 0, stream>>>(counts, offsets, blocksums, cursor, nNodes);

    gemm1_fill<<<gB + fillBlocks, 256, 0, stream>>>(
        nodes, W1T, b1f, G8, nNodes, edges, ew, cursor, csr, nEdges, gB, fillBlocks);

    node_fused<<<(nNodes + 31) / 32, 256, 0, stream>>>(
        nodes, G8, offsets, csr, W2T, b2f, out, nNodes);
}